// Round 2
// 364.522 us; speedup vs baseline: 1.0033x; 1.0033x over previous
//
#include <hip/hip_runtime.h>
#include <cstdint>

// Problem constants (fixed by the reference): B=8, N=16384, D=64, P=100.
#define NB    8
#define NN    16384
#define ND    64
#define NP    100
#define NPP   128          // theta rows padded (zeros) for MFMA K/N tiling
#define ST    1024         // sort threads per block (16 waves)
#define SE    16           // elements per sort thread (16384/1024)

typedef __attribute__((ext_vector_type(8))) short short8;   // 8 bf16 (4 VGPRs)
typedef __attribute__((ext_vector_type(4))) float f32x4;    // MFMA C/D

// ---------- bf16 convert (RNE) ----------
__device__ __forceinline__ short bf16c(float f) {
  uint32_t u = __float_as_uint(f);
  u = u + 0x7FFFu + ((u >> 16) & 1u);
  return (short)(u >> 16);
}

// ---------- sortable-key transforms ----------
__device__ __forceinline__ uint32_t f2s_u(uint32_t s) {
  return s ^ (((uint32_t)((int32_t)s >> 31)) | 0x80000000u);
}
__device__ __forceinline__ float s2f(uint32_t u) {
  uint32_t m = (u & 0x80000000u) ? 0x80000000u : 0xFFFFFFFFu;
  return __uint_as_float(u ^ m);
}

// LDS bank swizzle on word index (16B-contiguity-preserving)
__device__ __forceinline__ uint32_t swz(uint32_t w) {
  return w ^ ((w >> 3) & 0x1Cu);
}

// One LSD radix pass on 3-bit digit at shift sh, stable, in-place in S[16384].
// 16 waves: per-wave packed scan + 64-entry block scan in WG.
__device__ __forceinline__ void radix_pass(uint32_t (&k)[SE], uint32_t* S,
                                           uint32_t* WG, int tid, int sh,
                                           bool first) {
  const int lane = tid & 63;
  const int wave = tid >> 6;

  if (!first) {
#pragma unroll
    for (int q = 0; q < 4; q++) {
      uint32_t wb = ((uint32_t)tid << 4) + ((uint32_t)q << 2);
      uint4 v = *(const uint4*)(S + (wb ^ ((wb >> 3) & 0x1Cu)));
      k[4 * q + 0] = v.x; k[4 * q + 1] = v.y;
      k[4 * q + 2] = v.z; k[4 * q + 3] = v.w;
    }
  }

  // per-thread digit histogram packed 8 x 8-bit (counts <= 16)
  uint64_t c = 0;
#pragma unroll
  for (int e = 0; e < SE; e++) {
    uint32_t d = (k[e] >> sh) & 7u;
    c += 1ull << (d << 3);
  }

  uint32_t lo = (uint32_t)c, hi = (uint32_t)(c >> 32);
  uint32_t h[4], o[4];
  h[0] = (lo & 0xFFu) | ((lo & 0xFF00u) << 8);
  h[1] = ((lo >> 16) & 0xFFu) | ((lo >> 24) << 16);
  h[2] = (hi & 0xFFu) | ((hi & 0xFF00u) << 8);
  h[3] = ((hi >> 16) & 0xFFu) | ((hi >> 24) << 16);
#pragma unroll
  for (int i = 0; i < 4; i++) o[i] = h[i];

  // wave-level inclusive scan of packed (2x16-bit) counts
#pragma unroll
  for (int off = 1; off <= 32; off <<= 1) {
#pragma unroll
    for (int i = 0; i < 4; i++) {
      uint32_t t = __shfl_up(h[i], (unsigned)off, 64);
      if (lane >= off) h[i] += t;
    }
  }

  if (lane == 63) {
#pragma unroll
    for (int i = 0; i < 4; i++) WG[(wave << 2) + i] = h[i];
  }
  __syncthreads();

  // block scan across 16 waves x 4 packed words (64 entries, one wave)
  if (tid < 64) {
    uint32_t v = WG[tid];
    uint32_t own = v;
#pragma unroll
    for (int off = 4; off <= 32; off <<= 1) {
      uint32_t t = __shfl_up(v, (unsigned)off, 64);
      if (tid >= off) v += t;
    }
    uint32_t wexcl = v - own;                       // excl across waves, same word
    uint32_t grand = __shfl(v, 60 + (tid & 3), 64); // wave-15 inclusive = totals
    uint32_t gl = grand & 0xFFFFu, gh = grand >> 16;
    uint32_t ps = gl + gh, pincl = ps;
#pragma unroll
    for (int off = 1; off <= 2; off <<= 1) {
      uint32_t t = __shfl_up(pincl, (unsigned)off, 64);
      if ((tid & 3) >= off) pincl += t;
    }
    uint32_t pexcl = pincl - ps;                    // digit base for this word pair
    uint32_t g0 = pexcl + (wexcl & 0xFFFFu);
    uint32_t g1 = pexcl + gl + (wexcl >> 16);
    WG[tid] = g0 | (g1 << 16);
  }
  __syncthreads();

  uint32_t p0 = WG[(wave << 2) + 0] + (h[0] - o[0]);
  uint32_t p1 = WG[(wave << 2) + 1] + (h[1] - o[1]);
  uint32_t p2 = WG[(wave << 2) + 2] + (h[2] - o[2]);
  uint32_t p3 = WG[(wave << 2) + 3] + (h[3] - o[3]);
  uint64_t pc0 = (uint64_t)p0 | ((uint64_t)p1 << 32);
  uint64_t pc1 = (uint64_t)p2 | ((uint64_t)p3 << 32);

#pragma unroll
  for (int e = 0; e < SE; e++) {
    uint32_t d = (k[e] >> sh) & 7u;
    uint32_t s16 = (d & 3u) << 4;
    bool lo4 = d < 4u;
    uint64_t t = lo4 ? pc0 : pc1;
    uint32_t pos = (uint32_t)(t >> s16) & 0xFFFFu;
    uint64_t inc = 1ull << s16;
    pc0 += lo4 ? inc : 0ull;
    pc1 += lo4 ? 0ull : inc;
    S[swz(pos)] = k[e];
  }
  __syncthreads();
}

__device__ __forceinline__ void radix18(uint32_t (&k)[SE], uint32_t* S,
                                        uint32_t* WG, int tid) {
  bool first = true;
  for (int sh = 14; sh < 32; sh += 3) {
    radix_pass(k, S, WG, tid, sh, first);
    first = false;
  }
}

// ---------- kernel 1: normalize theta rows -> bf16, zero-padded to 128 ------
__global__ void normalize_theta(const float* __restrict__ theta,
                                ushort* __restrict__ thb) {
  const int p = blockIdx.x, t = threadIdx.x;
  if (p < NP) {
    float v = theta[p * ND + t];
    float ss = v * v;
#pragma unroll
    for (int off = 32; off >= 1; off >>= 1) ss += __shfl_xor(ss, off, 64);
    thb[p * ND + t] = (ushort)bf16c(v * rsqrtf(ss));
  } else {
    thb[p * ND + t] = 0;
  }
}

// ---------- kernel 2: MFMA projection ----------
// C[m=bn][n=p] = sum_k srcrow[m][k]*theta[p][k].  One wave = 16-row M-tile x
// 7 p-tiles of 16, K=64 = 2 chained mfma_f32_16x16x32_bf16.
__global__ __launch_bounds__(256) void project_mfma(
    const float* __restrict__ x, const float* __restrict__ y,
    const ushort* __restrict__ thb, float* __restrict__ xp,
    float* __restrict__ yp) {
  const int tid  = threadIdx.x;
  const int lane = tid & 63;
  const int quad = lane >> 4;
  const int mloc = lane & 15;
  const int wave = tid >> 6;

  const int blk    = blockIdx.x;        // 4096 blocks
  const int is_y   = blk & 1;
  const int rowblk = blk >> 1;          // 64 rows per rowblk
  const float* src = is_y ? y : x;
  float*       dst = is_y ? yp : xp;

  const int m0 = rowblk * 64 + wave * 16;       // wave's first global row
  const int b  = m0 >> 14;
  const int n0 = m0 & (NN - 1);

  const float* ap = src + (long)(m0 + mloc) * ND + quad * 8;
  float4 q0 = *(const float4*)(ap + 0);
  float4 q1 = *(const float4*)(ap + 4);
  float4 q2 = *(const float4*)(ap + 32);
  float4 q3 = *(const float4*)(ap + 36);
  short8 a0, a1;
  a0[0] = bf16c(q0.x); a0[1] = bf16c(q0.y); a0[2] = bf16c(q0.z); a0[3] = bf16c(q0.w);
  a0[4] = bf16c(q1.x); a0[5] = bf16c(q1.y); a0[6] = bf16c(q1.z); a0[7] = bf16c(q1.w);
  a1[0] = bf16c(q2.x); a1[1] = bf16c(q2.y); a1[2] = bf16c(q2.z); a1[3] = bf16c(q2.w);
  a1[4] = bf16c(q3.x); a1[5] = bf16c(q3.y); a1[6] = bf16c(q3.z); a1[7] = bf16c(q3.w);

  const f32x4 zero = {0.f, 0.f, 0.f, 0.f};
#pragma unroll
  for (int t = 0; t < 7; t++) {
    const int p = t * 16 + mloc;
    const short8 b0 = *(const short8*)(thb + p * ND + quad * 8);
    const short8 b1 = *(const short8*)(thb + p * ND + 32 + quad * 8);
    f32x4 acc = __builtin_amdgcn_mfma_f32_16x16x32_bf16(a0, b0, zero, 0, 0, 0);
    acc = __builtin_amdgcn_mfma_f32_16x16x32_bf16(a1, b1, acc, 0, 0, 0);
    if (t < 6 || mloc < (NP - 96)) {
      float* op = dst + ((long)b * NP + p) * NN + n0 + quad * 4;
      *(f32x4*)op = acc;   // rows quad*4+r are consecutive n -> float4
    }
  }
}

// ---------- kernel 3: per-(b,p) radix-sort y, rank x, write diff ----------
__global__ __launch_bounds__(ST, 8) void sort_diff_kernel(
    const float* __restrict__ xp, float* __restrict__ yp) {
  __shared__ uint32_t S[NN];    // 64 KB
  __shared__ uint32_t WG[64];
  const int tid = threadIdx.x;
  const long sbase = (long)blockIdx.x * NN;
  uint32_t k[SE];

  {
    const uint4* yg = (const uint4*)(yp + sbase) + (tid << 2);
#pragma unroll
    for (int q = 0; q < 4; q++) {
      uint4 v = yg[q];
      k[4 * q + 0] = f2s_u(v.x); k[4 * q + 1] = f2s_u(v.y);
      k[4 * q + 2] = f2s_u(v.z); k[4 * q + 3] = f2s_u(v.w);
    }
  }
  radix18(k, S, WG, tid);

  float ys[SE];
#pragma unroll
  for (int q = 0; q < 4; q++) {
    uint32_t wb = ((uint32_t)tid << 4) + ((uint32_t)q << 2);
    uint4 v = *(const uint4*)(S + (wb ^ ((wb >> 3) & 0x1Cu)));
    ys[4 * q + 0] = s2f(v.x); ys[4 * q + 1] = s2f(v.y);
    ys[4 * q + 2] = s2f(v.z); ys[4 * q + 3] = s2f(v.w);
  }

  {
    const uint4* xg = (const uint4*)(xp + sbase) + (tid << 2);
#pragma unroll
    for (int q = 0; q < 4; q++) {
      uint4 v = xg[q];
      uint32_t g = ((uint32_t)tid << 4) + (uint32_t)(q << 2);
      k[4 * q + 0] = (f2s_u(v.x) & 0xFFFFC000u) | (g + 0);
      k[4 * q + 1] = (f2s_u(v.y) & 0xFFFFC000u) | (g + 1);
      k[4 * q + 2] = (f2s_u(v.z) & 0xFFFFC000u) | (g + 2);
      k[4 * q + 3] = (f2s_u(v.w) & 0xFFFFC000u) | (g + 3);
    }
  }
  radix18(k, S, WG, tid);

#pragma unroll
  for (int q = 0; q < 4; q++) {
    uint32_t wb = ((uint32_t)tid << 4) + ((uint32_t)q << 2);
    uint4 v = *(const uint4*)(S + (wb ^ ((wb >> 3) & 0x1Cu)));
    k[4 * q + 0] = v.x & 0x3FFFu; k[4 * q + 1] = v.y & 0x3FFFu;
    k[4 * q + 2] = v.z & 0x3FFFu; k[4 * q + 3] = v.w & 0x3FFFu;
  }
  __syncthreads();

#pragma unroll
  for (int e = 0; e < SE; e++) {
    S[swz(k[e])] = __float_as_uint(ys[e]);
  }
  __syncthreads();

  const uint4* xg = (const uint4*)(xp + sbase) + (tid << 2);
  float4* og = (float4*)(yp + sbase) + (tid << 2);
#pragma unroll
  for (int q = 0; q < 4; q++) {
    uint32_t wb = ((uint32_t)tid << 4) + ((uint32_t)q << 2);
    uint4 v = *(const uint4*)(S + (wb ^ ((wb >> 3) & 0x1Cu)));
    uint4 xb = xg[q];
    float4 o;
    o.x = __uint_as_float(v.x) - __uint_as_float(xb.x);
    o.y = __uint_as_float(v.y) - __uint_as_float(xb.y);
    o.z = __uint_as_float(v.z) - __uint_as_float(xb.z);
    o.w = __uint_as_float(v.w) - __uint_as_float(xb.w);
    og[q] = o;
  }
}

// ---------- kernel 4: MFMA combine ----------
__global__ __launch_bounds__(256) void combine_mfma(
    const float* __restrict__ x, const float* __restrict__ diff,
    const ushort* __restrict__ thb, float* __restrict__ out) {
  const int tid  = threadIdx.x;
  const int lane = tid & 63;
  const int quad = lane >> 4;
  const int mloc = lane & 15;
  const int wave = tid >> 6;

  const int m0 = blockIdx.x * 64 + wave * 16;   // wave's first global row
  const int b  = m0 >> 14;
  const int n0 = m0 & (NN - 1);

  const float* dbase = diff + ((long)b * NP) * NN + n0 + mloc;
  short8 a[4];
#pragma unroll
  for (int kf = 0; kf < 4; kf++) {
#pragma unroll
    for (int j = 0; j < 8; j++) {
      const int p = kf * 32 + quad * 8 + j;
      const float v = (p < NP) ? dbase[(long)p * NN] : 0.0f;
      a[kf][j] = bf16c(v);
    }
  }

  const float inv = 1.0f / (float)NP;
  const f32x4 zero = {0.f, 0.f, 0.f, 0.f};
#pragma unroll
  for (int t = 0; t < 4; t++) {
    const int d = t * 16 + mloc;
    f32x4 acc = zero;
#pragma unroll
    for (int kf = 0; kf < 4; kf++) {
      short8 bf;
#pragma unroll
      for (int j = 0; j < 8; j++) {
        const int p = kf * 32 + quad * 8 + j;
        bf[j] = (short)thb[p * ND + d];
      }
      acc = __builtin_amdgcn_mfma_f32_16x16x32_bf16(a[kf], bf, acc, 0, 0, 0);
    }
#pragma unroll
    for (int r = 0; r < 4; r++) {
      const long off = (long)(m0 + quad * 4 + r) * ND + d;
      out[off] = x[off] + acc[r] * inv;
    }
  }
}

extern "C" void kernel_launch(void* const* d_in, const int* in_sizes, int n_in,
                              void* d_out, int out_size, void* d_ws, size_t ws_size,
                              hipStream_t stream) {
  const float* x     = (const float*)d_in[0];
  const float* y     = (const float*)d_in[1];
  const float* theta = (const float*)d_in[2];
  float* out = (float*)d_out;

  // workspace: [thb bf16 128x64: 16KB, pad 32KB][xp 52.4MB][yp/diff 52.4MB]
  ushort* thb = (ushort*)d_ws;
  float* xp = (float*)((char*)d_ws + (1 << 15));
  float* yp = xp + (size_t)NB * NP * NN;

  normalize_theta<<<dim3(NPP), dim3(ND), 0, stream>>>(theta, thb);
  project_mfma<<<dim3(2 * (NB * NN) / 64), dim3(256), 0, stream>>>(x, y, thb, xp, yp);
  sort_diff_kernel<<<dim3(NB * NP), dim3(ST), 0, stream>>>(xp, yp);
  combine_mfma<<<dim3((NB * NN) / 64), dim3(256), 0, stream>>>(x, yp, thb, out);
}